// Round 4
// baseline (385.395 us; speedup 1.0000x reference)
//
#include <hip/hip_runtime.h>

// Problem constants: B=2, C=64, H=W=256, KS=3, PAD=1, N=9, O=64
// Inputs NCHW fp32; activations internally NHWC bf16: addr = (h*256+w)*64 + c.
// Contraction index k = n*64 + c (n = 3x3 tap, c = channel).
//
// r4 decomposition: k_geom precomputes per-(pixel,tap) sampling records
// (8 B: u16 base lin, 4 mask bits, fp16 dx, fp16 dy); k_gconv does the
// gather + bilinear + conv MFMA with NO geometry and NO offset-conv in its
// dependency chain -- gather addresses are available at wave start.

typedef __attribute__((ext_vector_type(8))) short short8;     // 8 bf16 = 4 VGPRs
typedef __attribute__((ext_vector_type(4))) float float4a;    // MFMA accumulator
typedef __attribute__((ext_vector_type(2))) float f32x2;      // v_pk_* pair

// packed fp32x2 -> bf16x2 via HW cvt (RNE), 1 VALU op (gfx950; no builtin)
static __device__ __forceinline__ unsigned int cvtpk(float lo, float hi) {
    unsigned int r;
    asm("v_cvt_pk_bf16_f32 %0, %1, %2" : "=v"(r) : "v"(lo), "v"(hi));
    return r;
}
static __device__ __forceinline__ unsigned short f2bf(float f) {
    return (unsigned short)(cvtpk(f, f) & 0xffffu);
}
static __device__ __forceinline__ float bflo(unsigned int u) {
    return __builtin_bit_cast(float, u << 16);
}
static __device__ __forceinline__ float bfhi(unsigned int u) {
    return __builtin_bit_cast(float, u & 0xffff0000u);
}
// unpack 2 packed bf16 channels -> f32 pair
static __device__ __forceinline__ f32x2 up2(unsigned int u) {
    f32x2 r; r.x = bflo(u); r.y = bfhi(u); return r;
}
// bilinear combine, packed-f32 math (v_pk_fma candidates)
static __device__ __forceinline__ unsigned int comb2(unsigned int A, unsigned int B,
                                                     unsigned int C, unsigned int D,
                                                     f32x2 gx, f32x2 gy,
                                                     f32x2 gz, f32x2 gw) {
    f32x2 acc = gx * up2(A) + gy * up2(B) + gz * up2(C) + gw * up2(D);
    return cvtpk(acc.x, acc.y);
}

// ---------------------------------------------------------------------------
// One kernel packs all four weight tensors.
// w_conv [o][c][n] -> bf16 [o][k=n*64+c]; w_off [oc][c][n] -> bf16 [32][k], pad 0.
__global__ __launch_bounds__(256) void k_pack_all(const float* __restrict__ w1,
                                                  const float* __restrict__ w2,
                                                  const float* __restrict__ wo1,
                                                  const float* __restrict__ wo2,
                                                  unsigned short* __restrict__ w1b,
                                                  unsigned short* __restrict__ w2b,
                                                  unsigned short* __restrict__ wob1,
                                                  unsigned short* __restrict__ wob2) {
    int i = blockIdx.x * 256 + threadIdx.x;
    if (i < 36864) {
        int o = i / 576, r = i - o * 576, n = r >> 6, c = r & 63;
        w1b[i] = f2bf(w1[o * 576 + c * 9 + n]);
    } else if (i < 73728) {
        int j = i - 36864;
        int o = j / 576, r = j - o * 576, n = r >> 6, c = r & 63;
        w2b[j] = f2bf(w2[o * 576 + c * 9 + n]);
    } else if (i < 92160) {
        int j = i - 73728;
        int oc = j / 576, r = j - oc * 576, n = r >> 6, c = r & 63;
        wob1[j] = (oc < 18) ? f2bf(wo1[oc * 576 + c * 9 + n]) : (unsigned short)0;
    } else if (i < 110592) {
        int j = i - 92160;
        int oc = j / 576, r = j - oc * 576, n = r >> 6, c = r & 63;
        wob2[j] = (oc < 18) ? f2bf(wo2[oc * 576 + c * 9 + n]) : (unsigned short)0;
    }
}

// ---------------------------------------------------------------------------
// NCHW fp32 [64][65536] -> NHWC bf16 [65536][64]; grid (1024, B).
__global__ __launch_bounds__(256) void k_transpose_bf(const float* __restrict__ x,
                                                      unsigned short* __restrict__ xt) {
    __shared__ float tile[64][65];
    const float* xb = x + (size_t)blockIdx.y * 4194304;
    unsigned short* xtb = xt + (size_t)blockIdx.y * 4194304;
    const int p0 = blockIdx.x << 6;
    const int p = threadIdx.x & 63;
    const int c0 = threadIdx.x >> 6;   // 0..3
    #pragma unroll
    for (int i = 0; i < 16; ++i) {
        const int c = (i << 2) + c0;
        tile[p][c] = xb[(c << 16) + p0 + p];
    }
    __syncthreads();
    const int cq = (threadIdx.x & 15) << 2;
    const int pr0 = threadIdx.x >> 4;
    #pragma unroll
    for (int j = 0; j < 4; ++j) {
        const int pr = (j << 4) + pr0;
        uint2 u;
        u.x = cvtpk(tile[pr][cq + 0], tile[pr][cq + 1]);
        u.y = cvtpk(tile[pr][cq + 2], tile[pr][cq + 3]);
        *(uint2*)(xtb + ((p0 + pr) << 6) + cq) = u;
    }
}

// ---------------------------------------------------------------------------
// k_geom: offset conv + geometry -> 8 B records, one per (pixel, tap).
// Block = 256 thr = 4 INDEPENDENT waves, each owning a 16-px segment.
// Per wave: im2col loads direct from global (A-fragments in-register),
// 36 MFMA for the 18 offset channels, soff to wave-private LDS, then the
// record phase packs {u16 base, u8 mask, fp16 dx, fp16 dy}.
// Record semantics (exact vs reference): corner lins = (base+{0,257,1,256})
// mod 2^16 for unmasked corners; G = {(1-dx)(1-dy), dx dy, (1-dx)dy, dx(1-dy)},
// zeroed where masked. Wherever a corner is unmasked its coordinates are
// provably unclamped, so the compact form is exact.
__global__ __launch_bounds__(256) void k_geom(const unsigned short* __restrict__ src,
                                              const unsigned short* __restrict__ wob,
                                              const float* __restrict__ b_off,
                                              uint2* __restrict__ tbl,
                                              int row_base, int Rrows) {
    __shared__ float s_soff[4 * 320];   // 5120 B, wave-private
    const int b = blockIdx.z;
    const int h = row_base + blockIdx.y;
    const int tid = threadIdx.x;
    const int lane = tid & 63;
    const int wv = tid >> 6;
    const int l16 = lane & 15;          // pixel within segment
    const int q = lane >> 4;            // 0..3
    const int w0 = (blockIdx.x << 6) + (wv << 4);
    const unsigned short* srcb = src + ((size_t)b << 22);

    float4a aO0 = {0.f, 0.f, 0.f, 0.f};   // oc 0..15
    float4a aO1 = {0.f, 0.f, 0.f, 0.f};   // oc 16..31 (only 16,17 used)
    {
        const unsigned short* bo0 = wob + l16 * 576 + (q << 3);
        const unsigned short* bo1 = wob + (16 + l16) * 576 + (q << 3);
        #pragma unroll
        for (int t3 = 0; t3 < 3; ++t3) {
            uint4 v[6];
            #pragma unroll
            for (int j = 0; j < 3; ++j) {
                const int n = t3 * 3 + j;
                const int rn = n / 3, cn = n - rn * 3;
                const int row = h + rn - 1;
                const int col = w0 + l16 + cn - 1;
                const bool inb = (row >= 0) && (row < 256) && (col >= 0) && (col < 256);
                const int lin = inb ? ((row << 8) + col) : 0;
                uint4 v0 = *(const uint4*)(srcb + (lin << 6) + (q << 3));
                uint4 v1 = *(const uint4*)(srcb + (lin << 6) + ((q + 4) << 3));
                if (!inb) { v0.x = v0.y = v0.z = v0.w = 0u; v1.x = v1.y = v1.z = v1.w = 0u; }
                v[2 * j] = v0; v[2 * j + 1] = v1;
            }
            #pragma unroll
            for (int j = 0; j < 3; ++j) {
                const int n = t3 * 3 + j;
                const short8 a0 = __builtin_bit_cast(short8, v[2 * j]);
                const short8 a1 = __builtin_bit_cast(short8, v[2 * j + 1]);
                const short8 wf0a = *(const short8*)(bo0 + n * 64);
                const short8 wf0b = *(const short8*)(bo0 + n * 64 + 32);
                const short8 wf1a = *(const short8*)(bo1 + n * 64);
                const short8 wf1b = *(const short8*)(bo1 + n * 64 + 32);
                aO0 = __builtin_amdgcn_mfma_f32_16x16x32_bf16(a0, wf0a, aO0, 0, 0, 0);
                aO0 = __builtin_amdgcn_mfma_f32_16x16x32_bf16(a1, wf0b, aO0, 0, 0, 0);
                aO1 = __builtin_amdgcn_mfma_f32_16x16x32_bf16(a0, wf1a, aO1, 0, 0, 0);
                aO1 = __builtin_amdgcn_mfma_f32_16x16x32_bf16(a1, wf1b, aO1, 0, 0, 0);
            }
        }
    }
    float* soff = s_soff + wv * 320;
    {
        const float bia0 = b_off[l16];
        #pragma unroll
        for (int r = 0; r < 4; ++r)
            soff[(q * 4 + r) * 20 + l16] = aO0[r] + bia0;
        if (l16 < 2) {
            const float bia1 = b_off[16 + l16];
            #pragma unroll
            for (int r = 0; r < 4; ++r)
                soff[(q * 4 + r) * 20 + 16 + l16] = aO1[r] + bia1;
        }
    }
    // same-wave DS ordering: writes above, reads below, no barrier needed.

    uint2* trow = tbl + ((((size_t)(b * Rrows + blockIdx.y) << 8) + w0) * 9);
    #pragma unroll
    for (int i = 0; i < 3; ++i) {
        const int idx = i * 64 + lane;
        if (idx < 144) {
            const int px = idx / 9;
            const int n = idx - px * 9;
            const float ox = soff[px * 20 + n];
            const float oy = soff[px * 20 + 9 + n];
            const float pxx = ox + (float)(h + (n / 3));        // h+1 + (n/3-1)
            const float pyy = oy + (float)(w0 + px + (n % 3));  // w+1 + (n%3-1)
            const float fx = floorf(pxx), fy = floorf(pyy);
            const float qltx = fminf(fmaxf(fx, 0.f), 257.f);
            const float qlty = fminf(fmaxf(fy, 0.f), 257.f);
            const float qrbx = fminf(fmaxf(fx + 1.f, 0.f), 257.f);
            const float qrby = fminf(fmaxf(fy + 1.f, 0.f), 257.f);
            const int ilx = (int)qltx, ily = (int)qlty;
            const int irx = (int)qrbx, iry = (int)qrby;
            const unsigned int b0 = (ilx >= 1) && (ilx <= 256) && (ily >= 1) && (ily <= 256);
            const unsigned int b1 = (irx >= 1) && (irx <= 256) && (iry >= 1) && (iry <= 256);
            const unsigned int b2 = (ilx >= 1) && (ilx <= 256) && (iry >= 1) && (iry <= 256);
            const unsigned int b3 = (irx >= 1) && (irx <= 256) && (ily >= 1) && (ily <= 256);
            const float dx = pxx - fx;
            const float dy = pyy - fy;
            const unsigned int base =
                ((unsigned int)(((ilx - 1) << 8) + (ily - 1))) & 0xFFFFu;
            const unsigned int m = b0 | (b1 << 1) | (b2 << 2) | (b3 << 3);
            const unsigned int hx = __builtin_bit_cast(unsigned short, (_Float16)dx);
            const unsigned int hy = __builtin_bit_cast(unsigned short, (_Float16)dy);
            uint2 rec;
            rec.x = base | (m << 16);
            rec.y = hx | (hy << 16);
            trow[px * 9 + n] = rec;
        }
    }
}

// ---------------------------------------------------------------------------
// k_gconv: gather + bilinear + conv MFMA. Block = 256 thr = 4 waves per
// 16-px segment (r2 skeleton). Gather addresses come from the record table
// (5 x 8 B loads, ~30 VALU decode) -- issuable at wave start, no upstream
// MFMA/geometry in the chain. Tap split: g=0 -> {0,2,4,6,8}; g=1 -> {1,3,5,7,7}.
#define XSTR 584   // s_xoff row stride (bf16): dword stride 292 = 4 mod 32

__global__ __launch_bounds__(256, 4) void k_gconv(const unsigned short* __restrict__ src,
                                                  const uint2* __restrict__ tbl,
                                                  const unsigned short* __restrict__ wtb,
                                                  const float* __restrict__ addsrc,
                                                  void* __restrict__ out,
                                                  int relu, int nhwc_out,
                                                  int row_base, int Rrows) {
    __shared__ unsigned short s_xoff[16 * XSTR];   // 18688 B

    const int b = blockIdx.z;
    const int h = row_base + blockIdx.y;
    const int w0 = blockIdx.x << 4;
    const int tid = threadIdx.x;
    const int lane = tid & 63;
    const int wave = tid >> 6;
    const int quad = lane >> 4;
    const int l16 = lane & 15;

    const int px = tid >> 4;          // pixel 0..15
    const int oct = tid & 7;          // channel octet (8 bf16 = 16 B)
    const int g = (tid >> 3) & 1;     // tap group
    const unsigned short* srcb = src + ((size_t)b << 22);

    const int nT[5] = {g ? 1 : 0, g ? 3 : 2, g ? 5 : 4, g ? 7 : 6, g ? 7 : 8};

    // ---- record loads (available immediately) + decode ----
    const uint2* trow = tbl + ((((size_t)(b * Rrows + blockIdx.y) << 8) + w0) * 9);
    uint2 R[5];
    #pragma unroll
    for (int t = 0; t < 5; ++t) R[t] = trow[px * 9 + nT[t]];

    int4 L[5]; float4 G[5];
    #pragma unroll
    for (int t = 0; t < 5; ++t) {
        const unsigned int base = R[t].x & 0xFFFFu;
        const unsigned int m = R[t].x >> 16;
        const float dx = (float)__builtin_bit_cast(_Float16, (unsigned short)(R[t].y & 0xFFFFu));
        const float dy = (float)__builtin_bit_cast(_Float16, (unsigned short)(R[t].y >> 16));
        const float omx = 1.f - dx, omy = 1.f - dy;
        int4 li;
        li.x = (m & 1u) ? (int)base : 0;
        li.y = (m & 2u) ? (int)((base + 257u) & 0xFFFFu) : 0;
        li.z = (m & 4u) ? (int)((base + 1u) & 0xFFFFu) : 0;
        li.w = (m & 8u) ? (int)((base + 256u) & 0xFFFFu) : 0;
        L[t] = li;
        float4 gg;
        gg.x = (m & 1u) ? omx * omy : 0.f;
        gg.y = (m & 2u) ? dx * dy : 0.f;
        gg.z = (m & 4u) ? omx * dy : 0.f;
        gg.w = (m & 8u) ? dx * omy : 0.f;
        G[t] = gg;
    }

    short8 bfrag[18];   // conv B fragments, preloaded in two chunks below
    {
        const unsigned short* brow = wtb + (wave * 16 + l16) * 576 + quad * 8;

        // ---- round A: taps 0..2, 12 loads in flight ----
        uint4 A0, B0, C0, D0, A1, B1, C1, D1, A2, B2, C2, D2;
        A0 = *(const uint4*)(srcb + (L[0].x << 6) + (oct << 3));
        B0 = *(const uint4*)(srcb + (L[0].y << 6) + (oct << 3));
        C0 = *(const uint4*)(srcb + (L[0].z << 6) + (oct << 3));
        D0 = *(const uint4*)(srcb + (L[0].w << 6) + (oct << 3));
        A1 = *(const uint4*)(srcb + (L[1].x << 6) + (oct << 3));
        B1 = *(const uint4*)(srcb + (L[1].y << 6) + (oct << 3));
        C1 = *(const uint4*)(srcb + (L[1].z << 6) + (oct << 3));
        D1 = *(const uint4*)(srcb + (L[1].w << 6) + (oct << 3));
        A2 = *(const uint4*)(srcb + (L[2].x << 6) + (oct << 3));
        B2 = *(const uint4*)(srcb + (L[2].y << 6) + (oct << 3));
        C2 = *(const uint4*)(srcb + (L[2].z << 6) + (oct << 3));
        D2 = *(const uint4*)(srcb + (L[2].w << 6) + (oct << 3));
        {
            uint4 r;
            f32x2 gx, gy, gz, gw;
            gx = (f32x2){G[0].x, G[0].x}; gy = (f32x2){G[0].y, G[0].y};
            gz = (f32x2){G[0].z, G[0].z}; gw = (f32x2){G[0].w, G[0].w};
            r.x = comb2(A0.x, B0.x, C0.x, D0.x, gx, gy, gz, gw);
            r.y = comb2(A0.y, B0.y, C0.y, D0.y, gx, gy, gz, gw);
            r.z = comb2(A0.z, B0.z, C0.z, D0.z, gx, gy, gz, gw);
            r.w = comb2(A0.w, B0.w, C0.w, D0.w, gx, gy, gz, gw);
            *(uint4*)(s_xoff + px * XSTR + (nT[0] << 6) + (oct << 3)) = r;
            gx = (f32x2){G[1].x, G[1].x}; gy = (f32x2){G[1].y, G[1].y};
            gz = (f32x2){G[1].z, G[1].z}; gw = (f32x2){G[1].w, G[1].w};
            r.x = comb2(A1.x, B1.x, C1.x, D1.x, gx, gy, gz, gw);
            r.y = comb2(A1.y, B1.y, C1.y, D1.y, gx, gy, gz, gw);
            r.z = comb2(A1.z, B1.z, C1.z, D1.z, gx, gy, gz, gw);
            r.w = comb2(A1.w, B1.w, C1.w, D1.w, gx, gy, gz, gw);
            *(uint4*)(s_xoff + px * XSTR + (nT[1] << 6) + (oct << 3)) = r;
            gx = (f32x2){G[2].x, G[2].x}; gy = (f32x2){G[2].y, G[2].y};
            gz = (f32x2){G[2].z, G[2].z}; gw = (f32x2){G[2].w, G[2].w};
            r.x = comb2(A2.x, B2.x, C2.x, D2.x, gx, gy, gz, gw);
            r.y = comb2(A2.y, B2.y, C2.y, D2.y, gx, gy, gz, gw);
            r.z = comb2(A2.z, B2.z, C2.z, D2.z, gx, gy, gz, gw);
            r.w = comb2(A2.w, B2.w, C2.w, D2.w, gx, gy, gz, gw);
            *(uint4*)(s_xoff + px * XSTR + (nT[2] << 6) + (oct << 3)) = r;
        }

        // ---- round B: taps 3..4 (8 loads) + first 12 bfrag loads in flight ----
        uint4 A3, B3, C3, D3, A4, B4, C4, D4;
        A3 = *(const uint4*)(srcb + (L[3].x << 6) + (oct << 3));
        B3 = *(const uint4*)(srcb + (L[3].y << 6) + (oct << 3));
        C3 = *(const uint4*)(srcb + (L[3].z << 6) + (oct << 3));
        D3 = *(const uint4*)(srcb + (L[3].w << 6) + (oct << 3));
        A4 = *(const uint4*)(srcb + (L[4].x << 6) + (oct << 3));
        B4 = *(const uint4*)(srcb + (L[4].y << 6) + (oct << 3));
        C4 = *(const uint4*)(srcb + (L[4].z << 6) + (oct << 3));
        D4 = *(const uint4*)(srcb + (L[4].w << 6) + (oct << 3));
        #pragma unroll
        for (int ks = 0; ks < 12; ++ks)
            bfrag[ks] = *(const short8*)(brow + ks * 32);
        {
            uint4 r;
            f32x2 gx, gy, gz, gw;
            gx = (f32x2){G[3].x, G[3].x}; gy = (f32x2){G[3].y, G[3].y};
            gz = (f32x2){G[3].z, G[3].z}; gw = (f32x2){G[3].w, G[3].w};
            r.x = comb2(A3.x, B3.x, C3.x, D3.x, gx, gy, gz, gw);
            r.y = comb2(A3.y, B3.y, C3.y, D3.y, gx, gy, gz, gw);
            r.z = comb2(A3.z, B3.z, C3.z, D3.z, gx, gy, gz, gw);
            r.w = comb2(A3.w, B3.w, C3.w, D3.w, gx, gy, gz, gw);
            *(uint4*)(s_xoff + px * XSTR + (nT[3] << 6) + (oct << 3)) = r;
            gx = (f32x2){G[4].x, G[4].x}; gy = (f32x2){G[4].y, G[4].y};
            gz = (f32x2){G[4].z, G[4].z}; gw = (f32x2){G[4].w, G[4].w};
            r.x = comb2(A4.x, B4.x, C4.x, D4.x, gx, gy, gz, gw);
            r.y = comb2(A4.y, B4.y, C4.y, D4.y, gx, gy, gz, gw);
            r.z = comb2(A4.z, B4.z, C4.z, D4.z, gx, gy, gz, gw);
            r.w = comb2(A4.w, B4.w, C4.w, D4.w, gx, gy, gz, gw);
            *(uint4*)(s_xoff + px * XSTR + (nT[4] << 6) + (oct << 3)) = r;
        }
        #pragma unroll
        for (int ks = 12; ks < 18; ++ks)
            bfrag[ks] = *(const short8*)(brow + ks * 32);
    }
    __syncthreads();

    // ---- conv MFMA (LDS-only waits) + epilogue ----
    float4a acc = {0.f, 0.f, 0.f, 0.f};
    {
        const unsigned short* arow = s_xoff + l16 * XSTR + quad * 8;
        #pragma unroll
        for (int ks = 0; ks < 18; ++ks) {
            const short8 a = *(const short8*)(arow + ks * 32);
            acc = __builtin_amdgcn_mfma_f32_16x16x32_bf16(a, bfrag[ks], acc, 0, 0, 0);
        }
    }
    // D layout: col = oc = wave*16 + l16; row = px = quad*4 + r
    const int o = wave * 16 + l16;
    if (nhwc_out) {
        unsigned short* ob = (unsigned short*)out + ((size_t)b << 22);
        unsigned short* orow = ob + ((((h << 8) + w0) << 6)) + o;
        #pragma unroll
        for (int r = 0; r < 4; ++r) {
            float v = acc[r];
            if (relu) v = fmaxf(v, 0.f);
            orow[(size_t)((quad * 4 + r) << 6)] = f2bf(v);
        }
    } else {
        float* obf = (float*)out + ((size_t)b << 22);
        const int gidx = (o << 16) + (h << 8) + w0 + (quad << 2);
        float v0 = acc[0], v1 = acc[1], v2 = acc[2], v3 = acc[3];
        if (relu) {
            v0 = fmaxf(v0, 0.f); v1 = fmaxf(v1, 0.f);
            v2 = fmaxf(v2, 0.f); v3 = fmaxf(v3, 0.f);
        }
        if (addsrc != nullptr) {
            const float4 rv = *(const float4*)(addsrc + ((size_t)b << 22) + gidx);
            v0 += rv.x; v1 += rv.y; v2 += rv.z; v3 += rv.w;
        }
        float4 vv; vv.x = v0; vv.y = v1; vv.z = v2; vv.w = v3;
        *(float4*)(obf + gidx) = vv;
    }
}

// ---------------------------------------------------------------------------
extern "C" void kernel_launch(void* const* d_in, const int* in_sizes, int n_in,
                              void* d_out, int out_size, void* d_ws, size_t ws_size,
                              hipStream_t stream) {
    const float* x      = (const float*)d_in[0];
    const float* w_off1 = (const float*)d_in[1];
    const float* b_off1 = (const float*)d_in[2];
    const float* w1     = (const float*)d_in[3];
    const float* w_off2 = (const float*)d_in[4];
    const float* b_off2 = (const float*)d_in[5];
    const float* w2     = (const float*)d_in[6];
    float* outp = (float*)d_out;

    // workspace: 16 MB xT + 16 MB midT + packed weights + record table
    char* ws = (char*)d_ws;
    unsigned short* xT   = (unsigned short*)ws;                     // 16777216 B
    unsigned short* midT = (unsigned short*)(ws + 16777216);        // 16777216 B
    unsigned short* w1b  = (unsigned short*)(ws + 33554432);                    // 73728
    unsigned short* w2b  = (unsigned short*)(ws + 33554432 + 73728);            // 73728
    unsigned short* wob1 = (unsigned short*)(ws + 33554432 + 2 * 73728);        // 36864
    unsigned short* wob2 = (unsigned short*)(ws + 33554432 + 2 * 73728 + 36864);// 36864
    const size_t fixed = 33554432 + 2 * 73728 + 2 * 36864;          // 33,775,616
    uint2* tbl = (uint2*)(ws + fixed);

    // record table: 36,864 B per image row (both batches). Chunk rows if tight.
    int R = 256;
    if (ws_size != 0) {
        size_t avail = (ws_size > fixed) ? (ws_size - fixed) : 0;
        while (R > 32 && (size_t)R * 36864ull > avail) R >>= 1;
    }

    k_pack_all<<<432, 256, 0, stream>>>(w1, w2, w_off1, w_off2, w1b, w2b, wob1, wob2);

    dim3 gT(1024, 2);
    k_transpose_bf<<<gT, 256, 0, stream>>>(x, xT);

    // layer 1: offsets/geometry -> records; gather-conv(x), ReLU -> midT (NHWC)
    for (int r0 = 0; r0 < 256; r0 += R) {
        dim3 gG(4, R, 2), gC(16, R, 2);
        k_geom<<<gG, 256, 0, stream>>>(xT, wob1, b_off1, tbl, r0, R);
        k_gconv<<<gC, 256, 0, stream>>>(xT, tbl, w1b, nullptr, midT, 1, 1, r0, R);
    }
    // layer 2: offsets/geometry from mid; gather-conv(mid) + x residual -> out
    for (int r0 = 0; r0 < 256; r0 += R) {
        dim3 gG(4, R, 2), gC(16, R, 2);
        k_geom<<<gG, 256, 0, stream>>>(midT, wob2, b_off2, tbl, r0, R);
        k_gconv<<<gC, 256, 0, stream>>>(midT, tbl, w2b, x, outp, 0, 0, r0, R);
    }
}

// Round 6
// 359.900 us; speedup vs baseline: 1.0708x; 1.0708x over previous
//
#include <hip/hip_runtime.h>

// Problem constants: B=2, C=64, H=W=256, KS=3, PAD=1, N=9, O=64
// Inputs NCHW fp32; activations internally NHWC bf16: addr = (h*256+w)*64 + c.
// Contraction index k = n*64 + c (n = 3x3 tap, c = channel).
//
// r5 (resubmit; previous run died to a container-infra failure, no data):
// k_geom rebuilt with block-level LDS window staging (3 rows x 66 cols x
// 64 ch, oct-XOR swizzle) -- 3x fewer global load instrs, im2col on the LDS
// pipe. k_gconv is byte-identical to r4's proven 101 us version.

typedef __attribute__((ext_vector_type(8))) short short8;     // 8 bf16 = 4 VGPRs
typedef __attribute__((ext_vector_type(4))) float float4a;    // MFMA accumulator
typedef __attribute__((ext_vector_type(2))) float f32x2;      // v_pk_* pair

// packed fp32x2 -> bf16x2 via HW cvt (RNE), 1 VALU op (gfx950; no builtin)
static __device__ __forceinline__ unsigned int cvtpk(float lo, float hi) {
    unsigned int r;
    asm("v_cvt_pk_bf16_f32 %0, %1, %2" : "=v"(r) : "v"(lo), "v"(hi));
    return r;
}
static __device__ __forceinline__ unsigned short f2bf(float f) {
    return (unsigned short)(cvtpk(f, f) & 0xffffu);
}
static __device__ __forceinline__ float bflo(unsigned int u) {
    return __builtin_bit_cast(float, u << 16);
}
static __device__ __forceinline__ float bfhi(unsigned int u) {
    return __builtin_bit_cast(float, u & 0xffff0000u);
}
// unpack 2 packed bf16 channels -> f32 pair
static __device__ __forceinline__ f32x2 up2(unsigned int u) {
    f32x2 r; r.x = bflo(u); r.y = bfhi(u); return r;
}
// bilinear combine, packed-f32 math (v_pk_fma candidates)
static __device__ __forceinline__ unsigned int comb2(unsigned int A, unsigned int B,
                                                     unsigned int C, unsigned int D,
                                                     f32x2 gx, f32x2 gy,
                                                     f32x2 gz, f32x2 gw) {
    f32x2 acc = gx * up2(A) + gy * up2(B) + gz * up2(C) + gw * up2(D);
    return cvtpk(acc.x, acc.y);
}

// ---------------------------------------------------------------------------
// One kernel packs all four weight tensors.
// w_conv [o][c][n] -> bf16 [o][k=n*64+c]; w_off [oc][c][n] -> bf16 [32][k], pad 0.
__global__ __launch_bounds__(256) void k_pack_all(const float* __restrict__ w1,
                                                  const float* __restrict__ w2,
                                                  const float* __restrict__ wo1,
                                                  const float* __restrict__ wo2,
                                                  unsigned short* __restrict__ w1b,
                                                  unsigned short* __restrict__ w2b,
                                                  unsigned short* __restrict__ wob1,
                                                  unsigned short* __restrict__ wob2) {
    int i = blockIdx.x * 256 + threadIdx.x;
    if (i < 36864) {
        int o = i / 576, r = i - o * 576, n = r >> 6, c = r & 63;
        w1b[i] = f2bf(w1[o * 576 + c * 9 + n]);
    } else if (i < 73728) {
        int j = i - 36864;
        int o = j / 576, r = j - o * 576, n = r >> 6, c = r & 63;
        w2b[j] = f2bf(w2[o * 576 + c * 9 + n]);
    } else if (i < 92160) {
        int j = i - 73728;
        int oc = j / 576, r = j - oc * 576, n = r >> 6, c = r & 63;
        wob1[j] = (oc < 18) ? f2bf(wo1[oc * 576 + c * 9 + n]) : (unsigned short)0;
    } else if (i < 110592) {
        int j = i - 92160;
        int oc = j / 576, r = j - oc * 576, n = r >> 6, c = r & 63;
        wob2[j] = (oc < 18) ? f2bf(wo2[oc * 576 + c * 9 + n]) : (unsigned short)0;
    }
}

// ---------------------------------------------------------------------------
// NCHW fp32 [64][65536] -> NHWC bf16 [65536][64]; grid (1024, B).
__global__ __launch_bounds__(256) void k_transpose_bf(const float* __restrict__ x,
                                                      unsigned short* __restrict__ xt) {
    __shared__ float tile[64][65];
    const float* xb = x + (size_t)blockIdx.y * 4194304;
    unsigned short* xtb = xt + (size_t)blockIdx.y * 4194304;
    const int p0 = blockIdx.x << 6;
    const int p = threadIdx.x & 63;
    const int c0 = threadIdx.x >> 6;   // 0..3
    #pragma unroll
    for (int i = 0; i < 16; ++i) {
        const int c = (i << 2) + c0;
        tile[p][c] = xb[(c << 16) + p0 + p];
    }
    __syncthreads();
    const int cq = (threadIdx.x & 15) << 2;
    const int pr0 = threadIdx.x >> 4;
    #pragma unroll
    for (int j = 0; j < 4; ++j) {
        const int pr = (j << 4) + pr0;
        uint2 u;
        u.x = cvtpk(tile[pr][cq + 0], tile[pr][cq + 1]);
        u.y = cvtpk(tile[pr][cq + 2], tile[pr][cq + 3]);
        *(uint2*)(xtb + ((p0 + pr) << 6) + cq) = u;
    }
}

// ---------------------------------------------------------------------------
// k_geom (r5): offset conv + geometry -> 8 B records, one per (pixel, tap).
// Block = 256 thr = 4 waves covering 64 px of one row. The block stages a
// 3-row x 66-col x 64-ch bf16 window to LDS ONCE (coalesced 16B chunks,
// oct-XOR swizzle: phys_oct = o ^ (cl&7)), then each wave im2cols from LDS
// (~2-way banked), runs 36 MFMA for the 18 offset channels, writes soff to
// wave-private LDS (same-wave DS ordering, no barrier), and packs records
// {u16 base lin, 4 mask bits, fp16 dx, fp16 dy}.
// Record semantics (exact vs reference): corner lins = (base+{0,257,1,256})
// mod 2^16 for unmasked corners; G = {(1-dx)(1-dy), dx dy, (1-dx)dy, dx(1-dy)},
// zeroed where masked. Wherever a corner is unmasked its coordinates are
// provably unclamped, so the compact form is exact.
#define GW 66   // window cols

__global__ __launch_bounds__(256) void k_geom(const unsigned short* __restrict__ src,
                                              const unsigned short* __restrict__ wob,
                                              const float* __restrict__ b_off,
                                              uint2* __restrict__ tbl,
                                              int row_base, int Rrows) {
    __shared__ unsigned short s_win[3 * GW * 64];   // 25344 B
    __shared__ float          s_soff[4 * 320];      // 5120 B  (total 30464)

    const int b = blockIdx.z;
    const int h = row_base + blockIdx.y;
    const int tid = threadIdx.x;
    const int lane = tid & 63;
    const int wv = tid >> 6;
    const int l16 = lane & 15;          // pixel within wave segment
    const int q = lane >> 4;            // 0..3
    const int wb = blockIdx.x << 6;     // block px base (64 px)
    const int w0 = wb + (wv << 4);      // wave px base
    const unsigned short* srcb = src + ((size_t)b << 22);

    // ---- stage window: rows h-1..h+1, cols wb-1..wb+64 ----
    #pragma unroll
    for (int it = 0; it < 7; ++it) {
        const int i = it * 256 + tid;
        if (i < 1584) {                      // 3*66*8 chunks of 16 B
            const int o = i & 7;
            const int t = i >> 3;
            const int r = t / GW;
            const int cl = t - r * GW;
            const int row = h - 1 + r;
            const int col = wb - 1 + cl;
            const bool inb = (row >= 0) && (row < 256) && (col >= 0) && (col < 256);
            const int lin = inb ? ((row << 8) + col) : 0;
            uint4 v = *(const uint4*)(srcb + (lin << 6) + (o << 3));
            if (!inb) { v.x = 0u; v.y = 0u; v.z = 0u; v.w = 0u; }
            *(uint4*)(s_win + ((r * GW + cl) << 6) + ((o ^ (cl & 7)) << 3)) = v;
        }
    }
    __syncthreads();

    // ---- offset conv: im2col from LDS window, A-frags in-register ----
    float4a aO0 = {0.f, 0.f, 0.f, 0.f};   // oc 0..15
    float4a aO1 = {0.f, 0.f, 0.f, 0.f};   // oc 16..31 (only 16,17 used)
    {
        const unsigned short* bo0 = wob + l16 * 576 + (q << 3);
        const unsigned short* bo1 = wob + (16 + l16) * 576 + (q << 3);
        #pragma unroll
        for (int n = 0; n < 9; ++n) {
            const int rn = n / 3, cn = n - rn * 3;
            const int cl = (wv << 4) + l16 + cn;   // window col of (px, tap n)
            const int sw = cl & 7;
            const unsigned short* cell = s_win + ((rn * GW + cl) << 6);
            const short8 a0 = *(const short8*)(cell + ((q ^ sw) << 3));
            const short8 a1 = *(const short8*)(cell + (((q + 4) ^ sw) << 3));
            const short8 wf0a = *(const short8*)(bo0 + n * 64);
            const short8 wf0b = *(const short8*)(bo0 + n * 64 + 32);
            const short8 wf1a = *(const short8*)(bo1 + n * 64);
            const short8 wf1b = *(const short8*)(bo1 + n * 64 + 32);
            aO0 = __builtin_amdgcn_mfma_f32_16x16x32_bf16(a0, wf0a, aO0, 0, 0, 0);
            aO0 = __builtin_amdgcn_mfma_f32_16x16x32_bf16(a1, wf0b, aO0, 0, 0, 0);
            aO1 = __builtin_amdgcn_mfma_f32_16x16x32_bf16(a0, wf1a, aO1, 0, 0, 0);
            aO1 = __builtin_amdgcn_mfma_f32_16x16x32_bf16(a1, wf1b, aO1, 0, 0, 0);
        }
    }
    float* soff = s_soff + wv * 320;
    {
        const float bia0 = b_off[l16];
        #pragma unroll
        for (int r = 0; r < 4; ++r)
            soff[(q * 4 + r) * 20 + l16] = aO0[r] + bia0;
        if (l16 < 2) {
            const float bia1 = b_off[16 + l16];
            #pragma unroll
            for (int r = 0; r < 4; ++r)
                soff[(q * 4 + r) * 20 + 16 + l16] = aO1[r] + bia1;
        }
    }
    // same-wave DS ordering: writes above, reads below, no barrier needed.

    uint2* trow = tbl + ((((size_t)(b * Rrows + blockIdx.y) << 8) + w0) * 9);
    #pragma unroll
    for (int i = 0; i < 3; ++i) {
        const int idx = i * 64 + lane;
        if (idx < 144) {
            const int px = idx / 9;
            const int n = idx - px * 9;
            const float ox = soff[px * 20 + n];
            const float oy = soff[px * 20 + 9 + n];
            const float pxx = ox + (float)(h + (n / 3));        // h+1 + (n/3-1)
            const float pyy = oy + (float)(w0 + px + (n % 3));  // w+1 + (n%3-1)
            const float fx = floorf(pxx), fy = floorf(pyy);
            const float qltx = fminf(fmaxf(fx, 0.f), 257.f);
            const float qlty = fminf(fmaxf(fy, 0.f), 257.f);
            const float qrbx = fminf(fmaxf(fx + 1.f, 0.f), 257.f);
            const float qrby = fminf(fmaxf(fy + 1.f, 0.f), 257.f);
            const int ilx = (int)qltx, ily = (int)qlty;
            const int irx = (int)qrbx, iry = (int)qrby;
            const unsigned int b0 = (ilx >= 1) && (ilx <= 256) && (ily >= 1) && (ily <= 256);
            const unsigned int b1 = (irx >= 1) && (irx <= 256) && (iry >= 1) && (iry <= 256);
            const unsigned int b2 = (ilx >= 1) && (ilx <= 256) && (iry >= 1) && (iry <= 256);
            const unsigned int b3 = (irx >= 1) && (irx <= 256) && (ily >= 1) && (ily <= 256);
            const float dx = pxx - fx;
            const float dy = pyy - fy;
            const unsigned int base =
                ((unsigned int)(((ilx - 1) << 8) + (ily - 1))) & 0xFFFFu;
            const unsigned int m = b0 | (b1 << 1) | (b2 << 2) | (b3 << 3);
            const unsigned int hx = __builtin_bit_cast(unsigned short, (_Float16)dx);
            const unsigned int hy = __builtin_bit_cast(unsigned short, (_Float16)dy);
            uint2 rec;
            rec.x = base | (m << 16);
            rec.y = hx | (hy << 16);
            trow[px * 9 + n] = rec;
        }
    }
}

// ---------------------------------------------------------------------------
// k_gconv: gather + bilinear + conv MFMA. Block = 256 thr = 4 waves per
// 16-px segment (r2 skeleton). Gather addresses come from the record table
// (5 x 8 B loads, ~30 VALU decode) -- issuable at wave start, no upstream
// MFMA/geometry in the chain. Tap split: g=0 -> {0,2,4,6,8}; g=1 -> {1,3,5,7,7}.
// UNCHANGED from r4 (proven 101 us).
#define XSTR 584   // s_xoff row stride (bf16): dword stride 292 = 4 mod 32

__global__ __launch_bounds__(256, 4) void k_gconv(const unsigned short* __restrict__ src,
                                                  const uint2* __restrict__ tbl,
                                                  const unsigned short* __restrict__ wtb,
                                                  const float* __restrict__ addsrc,
                                                  void* __restrict__ out,
                                                  int relu, int nhwc_out,
                                                  int row_base, int Rrows) {
    __shared__ unsigned short s_xoff[16 * XSTR];   // 18688 B

    const int b = blockIdx.z;
    const int h = row_base + blockIdx.y;
    const int w0 = blockIdx.x << 4;
    const int tid = threadIdx.x;
    const int lane = tid & 63;
    const int wave = tid >> 6;
    const int quad = lane >> 4;
    const int l16 = lane & 15;

    const int px = tid >> 4;          // pixel 0..15
    const int oct = tid & 7;          // channel octet (8 bf16 = 16 B)
    const int g = (tid >> 3) & 1;     // tap group
    const unsigned short* srcb = src + ((size_t)b << 22);

    const int nT[5] = {g ? 1 : 0, g ? 3 : 2, g ? 5 : 4, g ? 7 : 6, g ? 7 : 8};

    // ---- record loads (available immediately) + decode ----
    const uint2* trow = tbl + ((((size_t)(b * Rrows + blockIdx.y) << 8) + w0) * 9);
    uint2 R[5];
    #pragma unroll
    for (int t = 0; t < 5; ++t) R[t] = trow[px * 9 + nT[t]];

    int4 L[5]; float4 G[5];
    #pragma unroll
    for (int t = 0; t < 5; ++t) {
        const unsigned int base = R[t].x & 0xFFFFu;
        const unsigned int m = R[t].x >> 16;
        const float dx = (float)__builtin_bit_cast(_Float16, (unsigned short)(R[t].y & 0xFFFFu));
        const float dy = (float)__builtin_bit_cast(_Float16, (unsigned short)(R[t].y >> 16));
        const float omx = 1.f - dx, omy = 1.f - dy;
        int4 li;
        li.x = (m & 1u) ? (int)base : 0;
        li.y = (m & 2u) ? (int)((base + 257u) & 0xFFFFu) : 0;
        li.z = (m & 4u) ? (int)((base + 1u) & 0xFFFFu) : 0;
        li.w = (m & 8u) ? (int)((base + 256u) & 0xFFFFu) : 0;
        L[t] = li;
        float4 gg;
        gg.x = (m & 1u) ? omx * omy : 0.f;
        gg.y = (m & 2u) ? dx * dy : 0.f;
        gg.z = (m & 4u) ? omx * dy : 0.f;
        gg.w = (m & 8u) ? dx * omy : 0.f;
        G[t] = gg;
    }

    short8 bfrag[18];   // conv B fragments, preloaded in two chunks below
    {
        const unsigned short* brow = wtb + (wave * 16 + l16) * 576 + quad * 8;

        // ---- round A: taps 0..2, 12 loads in flight ----
        uint4 A0, B0, C0, D0, A1, B1, C1, D1, A2, B2, C2, D2;
        A0 = *(const uint4*)(srcb + (L[0].x << 6) + (oct << 3));
        B0 = *(const uint4*)(srcb + (L[0].y << 6) + (oct << 3));
        C0 = *(const uint4*)(srcb + (L[0].z << 6) + (oct << 3));
        D0 = *(const uint4*)(srcb + (L[0].w << 6) + (oct << 3));
        A1 = *(const uint4*)(srcb + (L[1].x << 6) + (oct << 3));
        B1 = *(const uint4*)(srcb + (L[1].y << 6) + (oct << 3));
        C1 = *(const uint4*)(srcb + (L[1].z << 6) + (oct << 3));
        D1 = *(const uint4*)(srcb + (L[1].w << 6) + (oct << 3));
        A2 = *(const uint4*)(srcb + (L[2].x << 6) + (oct << 3));
        B2 = *(const uint4*)(srcb + (L[2].y << 6) + (oct << 3));
        C2 = *(const uint4*)(srcb + (L[2].z << 6) + (oct << 3));
        D2 = *(const uint4*)(srcb + (L[2].w << 6) + (oct << 3));
        {
            uint4 r;
            f32x2 gx, gy, gz, gw;
            gx = (f32x2){G[0].x, G[0].x}; gy = (f32x2){G[0].y, G[0].y};
            gz = (f32x2){G[0].z, G[0].z}; gw = (f32x2){G[0].w, G[0].w};
            r.x = comb2(A0.x, B0.x, C0.x, D0.x, gx, gy, gz, gw);
            r.y = comb2(A0.y, B0.y, C0.y, D0.y, gx, gy, gz, gw);
            r.z = comb2(A0.z, B0.z, C0.z, D0.z, gx, gy, gz, gw);
            r.w = comb2(A0.w, B0.w, C0.w, D0.w, gx, gy, gz, gw);
            *(uint4*)(s_xoff + px * XSTR + (nT[0] << 6) + (oct << 3)) = r;
            gx = (f32x2){G[1].x, G[1].x}; gy = (f32x2){G[1].y, G[1].y};
            gz = (f32x2){G[1].z, G[1].z}; gw = (f32x2){G[1].w, G[1].w};
            r.x = comb2(A1.x, B1.x, C1.x, D1.x, gx, gy, gz, gw);
            r.y = comb2(A1.y, B1.y, C1.y, D1.y, gx, gy, gz, gw);
            r.z = comb2(A1.z, B1.z, C1.z, D1.z, gx, gy, gz, gw);
            r.w = comb2(A1.w, B1.w, C1.w, D1.w, gx, gy, gz, gw);
            *(uint4*)(s_xoff + px * XSTR + (nT[1] << 6) + (oct << 3)) = r;
            gx = (f32x2){G[2].x, G[2].x}; gy = (f32x2){G[2].y, G[2].y};
            gz = (f32x2){G[2].z, G[2].z}; gw = (f32x2){G[2].w, G[2].w};
            r.x = comb2(A2.x, B2.x, C2.x, D2.x, gx, gy, gz, gw);
            r.y = comb2(A2.y, B2.y, C2.y, D2.y, gx, gy, gz, gw);
            r.z = comb2(A2.z, B2.z, C2.z, D2.z, gx, gy, gz, gw);
            r.w = comb2(A2.w, B2.w, C2.w, D2.w, gx, gy, gz, gw);
            *(uint4*)(s_xoff + px * XSTR + (nT[2] << 6) + (oct << 3)) = r;
        }

        // ---- round B: taps 3..4 (8 loads) + first 12 bfrag loads in flight ----
        uint4 A3, B3, C3, D3, A4, B4, C4, D4;
        A3 = *(const uint4*)(srcb + (L[3].x << 6) + (oct << 3));
        B3 = *(const uint4*)(srcb + (L[3].y << 6) + (oct << 3));
        C3 = *(const uint4*)(srcb + (L[3].z << 6) + (oct << 3));
        D3 = *(const uint4*)(srcb + (L[3].w << 6) + (oct << 3));
        A4 = *(const uint4*)(srcb + (L[4].x << 6) + (oct << 3));
        B4 = *(const uint4*)(srcb + (L[4].y << 6) + (oct << 3));
        C4 = *(const uint4*)(srcb + (L[4].z << 6) + (oct << 3));
        D4 = *(const uint4*)(srcb + (L[4].w << 6) + (oct << 3));
        #pragma unroll
        for (int ks = 0; ks < 12; ++ks)
            bfrag[ks] = *(const short8*)(brow + ks * 32);
        {
            uint4 r;
            f32x2 gx, gy, gz, gw;
            gx = (f32x2){G[3].x, G[3].x}; gy = (f32x2){G[3].y, G[3].y};
            gz = (f32x2){G[3].z, G[3].z}; gw = (f32x2){G[3].w, G[3].w};
            r.x = comb2(A3.x, B3.x, C3.x, D3.x, gx, gy, gz, gw);
            r.y = comb2(A3.y, B3.y, C3.y, D3.y, gx, gy, gz, gw);
            r.z = comb2(A3.z, B3.z, C3.z, D3.z, gx, gy, gz, gw);
            r.w = comb2(A3.w, B3.w, C3.w, D3.w, gx, gy, gz, gw);
            *(uint4*)(s_xoff + px * XSTR + (nT[3] << 6) + (oct << 3)) = r;
            gx = (f32x2){G[4].x, G[4].x}; gy = (f32x2){G[4].y, G[4].y};
            gz = (f32x2){G[4].z, G[4].z}; gw = (f32x2){G[4].w, G[4].w};
            r.x = comb2(A4.x, B4.x, C4.x, D4.x, gx, gy, gz, gw);
            r.y = comb2(A4.y, B4.y, C4.y, D4.y, gx, gy, gz, gw);
            r.z = comb2(A4.z, B4.z, C4.z, D4.z, gx, gy, gz, gw);
            r.w = comb2(A4.w, B4.w, C4.w, D4.w, gx, gy, gz, gw);
            *(uint4*)(s_xoff + px * XSTR + (nT[4] << 6) + (oct << 3)) = r;
        }
        #pragma unroll
        for (int ks = 12; ks < 18; ++ks)
            bfrag[ks] = *(const short8*)(brow + ks * 32);
    }
    __syncthreads();

    // ---- conv MFMA (LDS-only waits) + epilogue ----
    float4a acc = {0.f, 0.f, 0.f, 0.f};
    {
        const unsigned short* arow = s_xoff + l16 * XSTR + quad * 8;
        #pragma unroll
        for (int ks = 0; ks < 18; ++ks) {
            const short8 a = *(const short8*)(arow + ks * 32);
            acc = __builtin_amdgcn_mfma_f32_16x16x32_bf16(a, bfrag[ks], acc, 0, 0, 0);
        }
    }
    // D layout: col = oc = wave*16 + l16; row = px = quad*4 + r
    const int o = wave * 16 + l16;
    if (nhwc_out) {
        unsigned short* ob = (unsigned short*)out + ((size_t)b << 22);
        unsigned short* orow = ob + ((((h << 8) + w0) << 6)) + o;
        #pragma unroll
        for (int r = 0; r < 4; ++r) {
            float v = acc[r];
            if (relu) v = fmaxf(v, 0.f);
            orow[(size_t)((quad * 4 + r) << 6)] = f2bf(v);
        }
    } else {
        float* obf = (float*)out + ((size_t)b << 22);
        const int gidx = (o << 16) + (h << 8) + w0 + (quad << 2);
        float v0 = acc[0], v1 = acc[1], v2 = acc[2], v3 = acc[3];
        if (relu) {
            v0 = fmaxf(v0, 0.f); v1 = fmaxf(v1, 0.f);
            v2 = fmaxf(v2, 0.f); v3 = fmaxf(v3, 0.f);
        }
        if (addsrc != nullptr) {
            const float4 rv = *(const float4*)(addsrc + ((size_t)b << 22) + gidx);
            v0 += rv.x; v1 += rv.y; v2 += rv.z; v3 += rv.w;
        }
        float4 vv; vv.x = v0; vv.y = v1; vv.z = v2; vv.w = v3;
        *(float4*)(obf + gidx) = vv;
    }
}

// ---------------------------------------------------------------------------
extern "C" void kernel_launch(void* const* d_in, const int* in_sizes, int n_in,
                              void* d_out, int out_size, void* d_ws, size_t ws_size,
                              hipStream_t stream) {
    const float* x      = (const float*)d_in[0];
    const float* w_off1 = (const float*)d_in[1];
    const float* b_off1 = (const float*)d_in[2];
    const float* w1     = (const float*)d_in[3];
    const float* w_off2 = (const float*)d_in[4];
    const float* b_off2 = (const float*)d_in[5];
    const float* w2     = (const float*)d_in[6];
    float* outp = (float*)d_out;

    // workspace: 16 MB xT + 16 MB midT + packed weights + record table
    char* ws = (char*)d_ws;
    unsigned short* xT   = (unsigned short*)ws;                     // 16777216 B
    unsigned short* midT = (unsigned short*)(ws + 16777216);        // 16777216 B
    unsigned short* w1b  = (unsigned short*)(ws + 33554432);                    // 73728
    unsigned short* w2b  = (unsigned short*)(ws + 33554432 + 73728);            // 73728
    unsigned short* wob1 = (unsigned short*)(ws + 33554432 + 2 * 73728);        // 36864
    unsigned short* wob2 = (unsigned short*)(ws + 33554432 + 2 * 73728 + 36864);// 36864
    const size_t fixed = 33554432 + 2 * 73728 + 2 * 36864;          // 33,775,616
    uint2* tbl = (uint2*)(ws + fixed);

    // record table: 36,864 B per image row (both batches). Chunk rows if tight.
    int R = 256;
    if (ws_size != 0) {
        size_t avail = (ws_size > fixed) ? (ws_size - fixed) : 0;
        while (R > 32 && (size_t)R * 36864ull > avail) R >>= 1;
    }

    k_pack_all<<<432, 256, 0, stream>>>(w1, w2, w_off1, w_off2, w1b, w2b, wob1, wob2);

    dim3 gT(1024, 2);
    k_transpose_bf<<<gT, 256, 0, stream>>>(x, xT);

    // layer 1: offsets/geometry -> records; gather-conv(x), ReLU -> midT (NHWC)
    for (int r0 = 0; r0 < 256; r0 += R) {
        dim3 gG(4, R, 2), gC(16, R, 2);
        k_geom<<<gG, 256, 0, stream>>>(xT, wob1, b_off1, tbl, r0, R);
        k_gconv<<<gC, 256, 0, stream>>>(xT, tbl, w1b, nullptr, midT, 1, 1, r0, R);
    }
    // layer 2: offsets/geometry from mid; gather-conv(mid) + x residual -> out
    for (int r0 = 0; r0 < 256; r0 += R) {
        dim3 gG(4, R, 2), gC(16, R, 2);
        k_geom<<<gG, 256, 0, stream>>>(midT, wob2, b_off2, tbl, r0, R);
        k_gconv<<<gC, 256, 0, stream>>>(midT, tbl, w2b, x, outp, 0, 0, r0, R);
    }
}

// Round 7
// 234.039 us; speedup vs baseline: 1.6467x; 1.5378x over previous
//
#include <hip/hip_runtime.h>

// Problem constants: B=2, C=64, H=W=256, KS=3, PAD=1, N=9, O=64
// Inputs NCHW fp32; activations internally NHWC bf16: addr = (h*256+w)*64 + c.
// Contraction index k = n*64 + c (n = 3x3 tap, c = channel).
//
// r7: (1) fragment-major weight packing: B-fragment wave loads become
// contiguous 1KB spans (8 L1 txns vs 16 per wave instruction) in BOTH k_geom
// and k_gconv. (2) k_gconv processes 2 segments per block, with segment-1's
// round-A gathers issued BEFORE the barrier so their latency hides under
// segment-0's MFMA+epilogue (T14 async-stage pattern).

typedef __attribute__((ext_vector_type(8))) short short8;     // 8 bf16 = 4 VGPRs
typedef __attribute__((ext_vector_type(4))) float float4a;    // MFMA accumulator
typedef __attribute__((ext_vector_type(2))) float f32x2;      // v_pk_* pair

// packed fp32x2 -> bf16x2 via HW cvt (RNE), 1 VALU op (gfx950; no builtin)
static __device__ __forceinline__ unsigned int cvtpk(float lo, float hi) {
    unsigned int r;
    asm("v_cvt_pk_bf16_f32 %0, %1, %2" : "=v"(r) : "v"(lo), "v"(hi));
    return r;
}
static __device__ __forceinline__ unsigned short f2bf(float f) {
    return (unsigned short)(cvtpk(f, f) & 0xffffu);
}
static __device__ __forceinline__ float bflo(unsigned int u) {
    return __builtin_bit_cast(float, u << 16);
}
static __device__ __forceinline__ float bfhi(unsigned int u) {
    return __builtin_bit_cast(float, u & 0xffff0000u);
}
static __device__ __forceinline__ f32x2 up2(unsigned int u) {
    f32x2 r; r.x = bflo(u); r.y = bfhi(u); return r;
}
// bilinear combine, packed-f32 math
static __device__ __forceinline__ unsigned int comb2(unsigned int A, unsigned int B,
                                                     unsigned int C, unsigned int D,
                                                     f32x2 gx, f32x2 gy,
                                                     f32x2 gz, f32x2 gw) {
    f32x2 acc = gx * up2(A) + gy * up2(B) + gz * up2(C) + gw * up2(D);
    return cvtpk(acc.x, acc.y);
}
// 4-corner combine of a 16B (8-channel) group
static __device__ __forceinline__ uint4 comb16(const uint4 V0, const uint4 V1,
                                               const uint4 V2, const uint4 V3,
                                               float4 g) {
    f32x2 gx; gx.x = g.x; gx.y = g.x;
    f32x2 gy; gy.x = g.y; gy.y = g.y;
    f32x2 gz; gz.x = g.z; gz.y = g.z;
    f32x2 gw; gw.x = g.w; gw.y = g.w;
    uint4 r;
    r.x = comb2(V0.x, V1.x, V2.x, V3.x, gx, gy, gz, gw);
    r.y = comb2(V0.y, V1.y, V2.y, V3.y, gx, gy, gz, gw);
    r.z = comb2(V0.z, V1.z, V2.z, V3.z, gx, gy, gz, gw);
    r.w = comb2(V0.w, V1.w, V2.w, V3.w, gx, gy, gz, gw);
    return r;
}
// record decode: {u16 base lin, 4 mask bits, fp16 dx, fp16 dy} -> 4 lins + 4 g
static __device__ __forceinline__ void decode_rec(const uint2 r, int4& li, float4& gg) {
    const unsigned int base = r.x & 0xFFFFu;
    const unsigned int m = r.x >> 16;
    const float dx = (float)__builtin_bit_cast(_Float16, (unsigned short)(r.y & 0xFFFFu));
    const float dy = (float)__builtin_bit_cast(_Float16, (unsigned short)(r.y >> 16));
    const float omx = 1.f - dx, omy = 1.f - dy;
    li.x = (m & 1u) ? (int)base : 0;
    li.y = (m & 2u) ? (int)((base + 257u) & 0xFFFFu) : 0;
    li.z = (m & 4u) ? (int)((base + 1u) & 0xFFFFu) : 0;
    li.w = (m & 8u) ? (int)((base + 256u) & 0xFFFFu) : 0;
    gg.x = (m & 1u) ? omx * omy : 0.f;
    gg.y = (m & 2u) ? dx * dy : 0.f;
    gg.z = (m & 4u) ? omx * dy : 0.f;
    gg.w = (m & 8u) ? dx * omy : 0.f;
}

// ---------------------------------------------------------------------------
// Pack all four weight tensors, FRAGMENT-MAJOR:
// dst index = ((wv*18 + ks)*64 + lane)*8 + j, where wv = row>>4,
// lane = ((k>>3)&3)*16 + (row&15), ks = k>>5, j = k&7, k = n*64 + c.
// A wave's B-frag load for (wv, ks) is then a contiguous 1KB span.
__global__ __launch_bounds__(256) void k_pack_all(const float* __restrict__ w1,
                                                  const float* __restrict__ w2,
                                                  const float* __restrict__ wo1,
                                                  const float* __restrict__ wo2,
                                                  unsigned short* __restrict__ w1b,
                                                  unsigned short* __restrict__ w2b,
                                                  unsigned short* __restrict__ wob1,
                                                  unsigned short* __restrict__ wob2) {
    int i = blockIdx.x * 256 + threadIdx.x;
    if (i < 36864) {
        int o = i / 576, k = i - o * 576, n = k >> 6, c = k & 63;
        int dst = (((o >> 4) * 18 + (k >> 5)) * 64 + (((k >> 3) & 3) << 4) + (o & 15)) * 8 + (k & 7);
        w1b[dst] = f2bf(w1[o * 576 + c * 9 + n]);
    } else if (i < 73728) {
        int j = i - 36864;
        int o = j / 576, k = j - o * 576, n = k >> 6, c = k & 63;
        int dst = (((o >> 4) * 18 + (k >> 5)) * 64 + (((k >> 3) & 3) << 4) + (o & 15)) * 8 + (k & 7);
        w2b[dst] = f2bf(w2[o * 576 + c * 9 + n]);
    } else if (i < 92160) {
        int j = i - 73728;
        int oc = j / 576, k = j - oc * 576, n = k >> 6, c = k & 63;
        int dst = (((oc >> 4) * 18 + (k >> 5)) * 64 + (((k >> 3) & 3) << 4) + (oc & 15)) * 8 + (k & 7);
        wob1[dst] = (oc < 18) ? f2bf(wo1[oc * 576 + c * 9 + n]) : (unsigned short)0;
    } else if (i < 110592) {
        int j = i - 92160;
        int oc = j / 576, k = j - oc * 576, n = k >> 6, c = k & 63;
        int dst = (((oc >> 4) * 18 + (k >> 5)) * 64 + (((k >> 3) & 3) << 4) + (oc & 15)) * 8 + (k & 7);
        wob2[dst] = (oc < 18) ? f2bf(wo2[oc * 576 + c * 9 + n]) : (unsigned short)0;
    }
}

// ---------------------------------------------------------------------------
// NCHW fp32 [64][65536] -> NHWC bf16 [65536][64]; grid (1024, B).
__global__ __launch_bounds__(256) void k_transpose_bf(const float* __restrict__ x,
                                                      unsigned short* __restrict__ xt) {
    __shared__ float tile[64][65];
    const float* xb = x + (size_t)blockIdx.y * 4194304;
    unsigned short* xtb = xt + (size_t)blockIdx.y * 4194304;
    const int p0 = blockIdx.x << 6;
    const int p = threadIdx.x & 63;
    const int c0 = threadIdx.x >> 6;   // 0..3
    #pragma unroll
    for (int i = 0; i < 16; ++i) {
        const int c = (i << 2) + c0;
        tile[p][c] = xb[(c << 16) + p0 + p];
    }
    __syncthreads();
    const int cq = (threadIdx.x & 15) << 2;
    const int pr0 = threadIdx.x >> 4;
    #pragma unroll
    for (int j = 0; j < 4; ++j) {
        const int pr = (j << 4) + pr0;
        uint2 u;
        u.x = cvtpk(tile[pr][cq + 0], tile[pr][cq + 1]);
        u.y = cvtpk(tile[pr][cq + 2], tile[pr][cq + 3]);
        *(uint2*)(xtb + ((p0 + pr) << 6) + cq) = u;
    }
}

// ---------------------------------------------------------------------------
// k_geom: offset conv + geometry -> 8 B records, one per (pixel, tap).
// r5 structure (LDS window) + fragment-major wf loads (8 txns vs 16).
#define GW 66   // window cols

__global__ __launch_bounds__(256) void k_geom(const unsigned short* __restrict__ src,
                                              const unsigned short* __restrict__ wob,
                                              const float* __restrict__ b_off,
                                              uint2* __restrict__ tbl,
                                              int row_base, int Rrows) {
    __shared__ unsigned short s_win[3 * GW * 64];   // 25344 B
    __shared__ float          s_soff[4 * 320];      // 5120 B

    const int b = blockIdx.z;
    const int h = row_base + blockIdx.y;
    const int tid = threadIdx.x;
    const int lane = tid & 63;
    const int wv = tid >> 6;
    const int l16 = lane & 15;
    const int q = lane >> 4;
    const int wb = blockIdx.x << 6;
    const int w0 = wb + (wv << 4);
    const unsigned short* srcb = src + ((size_t)b << 22);

    // ---- stage window: rows h-1..h+1, cols wb-1..wb+64, oct-XOR swizzle ----
    #pragma unroll
    for (int it = 0; it < 7; ++it) {
        const int i = it * 256 + tid;
        if (i < 1584) {
            const int o = i & 7;
            const int t = i >> 3;
            const int r = t / GW;
            const int cl = t - r * GW;
            const int row = h - 1 + r;
            const int col = wb - 1 + cl;
            const bool inb = (row >= 0) && (row < 256) && (col >= 0) && (col < 256);
            const int lin = inb ? ((row << 8) + col) : 0;
            uint4 v = *(const uint4*)(srcb + (lin << 6) + (o << 3));
            if (!inb) { v.x = 0u; v.y = 0u; v.z = 0u; v.w = 0u; }
            *(uint4*)(s_win + ((r * GW + cl) << 6) + ((o ^ (cl & 7)) << 3)) = v;
        }
    }
    __syncthreads();

    // ---- offset conv: im2col from LDS window; fragment-major weights ----
    float4a aO0 = {0.f, 0.f, 0.f, 0.f};   // oc 0..15
    float4a aO1 = {0.f, 0.f, 0.f, 0.f};   // oc 16..31 (only 16,17 used)
    {
        const unsigned short* bo0 = wob + lane * 8;          // wv=0 rows
        const unsigned short* bo1 = wob + 9216 + lane * 8;   // wv=1 rows
        #pragma unroll
        for (int n = 0; n < 9; ++n) {
            const int rn = n / 3, cn = n - rn * 3;
            const int cl = (wv << 4) + l16 + cn;
            const int sw = cl & 7;
            const unsigned short* cell = s_win + ((rn * GW + cl) << 6);
            const short8 a0 = *(const short8*)(cell + ((q ^ sw) << 3));
            const short8 a1 = *(const short8*)(cell + (((q + 4) ^ sw) << 3));
            const short8 wf0a = *(const short8*)(bo0 + (2 * n) * 512);
            const short8 wf0b = *(const short8*)(bo0 + (2 * n + 1) * 512);
            const short8 wf1a = *(const short8*)(bo1 + (2 * n) * 512);
            const short8 wf1b = *(const short8*)(bo1 + (2 * n + 1) * 512);
            aO0 = __builtin_amdgcn_mfma_f32_16x16x32_bf16(a0, wf0a, aO0, 0, 0, 0);
            aO0 = __builtin_amdgcn_mfma_f32_16x16x32_bf16(a1, wf0b, aO0, 0, 0, 0);
            aO1 = __builtin_amdgcn_mfma_f32_16x16x32_bf16(a0, wf1a, aO1, 0, 0, 0);
            aO1 = __builtin_amdgcn_mfma_f32_16x16x32_bf16(a1, wf1b, aO1, 0, 0, 0);
        }
    }
    float* soff = s_soff + wv * 320;
    {
        const float bia0 = b_off[l16];
        #pragma unroll
        for (int r = 0; r < 4; ++r)
            soff[(q * 4 + r) * 20 + l16] = aO0[r] + bia0;
        if (l16 < 2) {
            const float bia1 = b_off[16 + l16];
            #pragma unroll
            for (int r = 0; r < 4; ++r)
                soff[(q * 4 + r) * 20 + 16 + l16] = aO1[r] + bia1;
        }
    }
    // same-wave DS ordering: writes above, reads below, no barrier needed.

    uint2* trow = tbl + ((((size_t)(b * Rrows + blockIdx.y) << 8) + w0) * 9);
    #pragma unroll
    for (int i = 0; i < 3; ++i) {
        const int idx = i * 64 + lane;
        if (idx < 144) {
            const int px = idx / 9;
            const int n = idx - px * 9;
            const float ox = soff[px * 20 + n];
            const float oy = soff[px * 20 + 9 + n];
            const float pxx = ox + (float)(h + (n / 3));
            const float pyy = oy + (float)(w0 + px + (n % 3));
            const float fx = floorf(pxx), fy = floorf(pyy);
            const float qltx = fminf(fmaxf(fx, 0.f), 257.f);
            const float qlty = fminf(fmaxf(fy, 0.f), 257.f);
            const float qrbx = fminf(fmaxf(fx + 1.f, 0.f), 257.f);
            const float qrby = fminf(fmaxf(fy + 1.f, 0.f), 257.f);
            const int ilx = (int)qltx, ily = (int)qlty;
            const int irx = (int)qrbx, iry = (int)qrby;
            const unsigned int b0 = (ilx >= 1) && (ilx <= 256) && (ily >= 1) && (ily <= 256);
            const unsigned int b1 = (irx >= 1) && (irx <= 256) && (iry >= 1) && (iry <= 256);
            const unsigned int b2 = (ilx >= 1) && (ilx <= 256) && (iry >= 1) && (iry <= 256);
            const unsigned int b3 = (irx >= 1) && (irx <= 256) && (ily >= 1) && (ily <= 256);
            const float dx = pxx - fx;
            const float dy = pyy - fy;
            const unsigned int base =
                ((unsigned int)(((ilx - 1) << 8) + (ily - 1))) & 0xFFFFu;
            const unsigned int m = b0 | (b1 << 1) | (b2 << 2) | (b3 << 3);
            const unsigned int hx = __builtin_bit_cast(unsigned short, (_Float16)dx);
            const unsigned int hy = __builtin_bit_cast(unsigned short, (_Float16)dy);
            uint2 rec;
            rec.x = base | (m << 16);
            rec.y = hx | (hy << 16);
            trow[px * 9 + n] = rec;
        }
    }
}

// ---------------------------------------------------------------------------
// k_gconv (r7): 2 segments per block (32 px), pipelined.
//   recs S0+S1 -> decode S0 -> S0 gathers/comb2 -> decode S1 + issue S1-roundA
//   -> barrier -> MFMA S0 + epilogue S0 (S1-A in flight) -> barrier
//   -> issue S1-roundB -> comb2 S1-A (hides B) -> comb2 S1-B -> barrier
//   -> MFMA S1 + epilogue S1.
// Weights fragment-major: B-frag load = contiguous 1KB span per wave instr.
#define XSTR 584   // s_xoff row stride (bf16): dword stride 292 = 4 mod 32

template<int TN>
static __device__ __forceinline__ void gather_round(const unsigned short* __restrict__ srcb,
                                                    int oct, const int4* L, const float4* G,
                                                    const int* nT, int t0,
                                                    unsigned short* __restrict__ s_dst) {
    uint4 V[TN][4];
    #pragma unroll
    for (int t = 0; t < TN; ++t) {
        V[t][0] = *(const uint4*)(srcb + (L[t0 + t].x << 6) + (oct << 3));
        V[t][1] = *(const uint4*)(srcb + (L[t0 + t].y << 6) + (oct << 3));
        V[t][2] = *(const uint4*)(srcb + (L[t0 + t].z << 6) + (oct << 3));
        V[t][3] = *(const uint4*)(srcb + (L[t0 + t].w << 6) + (oct << 3));
    }
    #pragma unroll
    for (int t = 0; t < TN; ++t) {
        const uint4 r = comb16(V[t][0], V[t][1], V[t][2], V[t][3], G[t0 + t]);
        *(uint4*)(s_dst + (nT[t0 + t] << 6) + (oct << 3)) = r;
    }
}

static __device__ __forceinline__ void epilogue_seg(float4a acc, int b, int h, int segw,
                                                    int wave, int quad, int l16,
                                                    int relu, int nhwc_out,
                                                    const float* __restrict__ addsrc,
                                                    void* __restrict__ out) {
    const int o = wave * 16 + l16;
    if (nhwc_out) {
        unsigned short* ob = (unsigned short*)out + ((size_t)b << 22);
        unsigned short* orow = ob + ((((h << 8) + segw) << 6)) + o;
        #pragma unroll
        for (int r = 0; r < 4; ++r) {
            float v = acc[r];
            if (relu) v = fmaxf(v, 0.f);
            orow[(size_t)((quad * 4 + r) << 6)] = f2bf(v);
        }
    } else {
        float* obf = (float*)out + ((size_t)b << 22);
        const int gidx = (o << 16) + (h << 8) + segw + (quad << 2);
        float v0 = acc[0], v1 = acc[1], v2 = acc[2], v3 = acc[3];
        if (relu) {
            v0 = fmaxf(v0, 0.f); v1 = fmaxf(v1, 0.f);
            v2 = fmaxf(v2, 0.f); v3 = fmaxf(v3, 0.f);
        }
        if (addsrc != nullptr) {
            const float4 rv = *(const float4*)(addsrc + ((size_t)b << 22) + gidx);
            v0 += rv.x; v1 += rv.y; v2 += rv.z; v3 += rv.w;
        }
        float4 vv; vv.x = v0; vv.y = v1; vv.z = v2; vv.w = v3;
        *(float4*)(obf + gidx) = vv;
    }
}

__global__ __launch_bounds__(256, 3) void k_gconv(const unsigned short* __restrict__ src,
                                                  const uint2* __restrict__ tbl,
                                                  const unsigned short* __restrict__ wtb,
                                                  const float* __restrict__ addsrc,
                                                  void* __restrict__ out,
                                                  int relu, int nhwc_out,
                                                  int row_base, int Rrows) {
    __shared__ unsigned short s_xoff[16 * XSTR];   // 18688 B, reused per segment

    const int b = blockIdx.z;
    const int h = row_base + blockIdx.y;
    const int w0 = blockIdx.x << 5;   // 32 px per block (2 segments)
    const int tid = threadIdx.x;
    const int lane = tid & 63;
    const int wave = tid >> 6;
    const int quad = lane >> 4;
    const int l16 = lane & 15;

    const int px = tid >> 4;          // pixel 0..15 within segment
    const int oct = tid & 7;          // channel octet (8 bf16 = 16 B)
    const int g = (tid >> 3) & 1;     // tap group
    const unsigned short* srcb = src + ((size_t)b << 22);

    const int nT[5] = {g ? 1 : 0, g ? 3 : 2, g ? 5 : 4, g ? 7 : 6, g ? 7 : 8};

    // ---- record loads for BOTH segments (available immediately) ----
    const uint2* trow = tbl + ((((size_t)(b * Rrows + blockIdx.y) << 8) + w0) * 9);
    uint2 R0[5], R1[5];
    #pragma unroll
    for (int t = 0; t < 5; ++t) R0[t] = trow[px * 9 + nT[t]];
    #pragma unroll
    for (int t = 0; t < 5; ++t) R1[t] = trow[(16 + px) * 9 + nT[t]];

    int4 L0[5]; float4 G0[5];
    #pragma unroll
    for (int t = 0; t < 5; ++t) decode_rec(R0[t], L0[t], G0[t]);

    unsigned short* s_dst = s_xoff + px * XSTR;

    // ---- segment 0: gather + bilinear -> s_xoff ----
    gather_round<3>(srcb, oct, L0, G0, nT, 0, s_dst);
    gather_round<2>(srcb, oct, L0, G0, nT, 3, s_dst);

    // ---- decode S1 and issue S1 round-A gathers BEFORE the barrier ----
    int4 L1[5]; float4 G1[5];
    #pragma unroll
    for (int t = 0; t < 5; ++t) decode_rec(R1[t], L1[t], G1[t]);
    uint4 E[3][4];
    #pragma unroll
    for (int t = 0; t < 3; ++t) {
        E[t][0] = *(const uint4*)(srcb + (L1[t].x << 6) + (oct << 3));
        E[t][1] = *(const uint4*)(srcb + (L1[t].y << 6) + (oct << 3));
        E[t][2] = *(const uint4*)(srcb + (L1[t].z << 6) + (oct << 3));
        E[t][3] = *(const uint4*)(srcb + (L1[t].w << 6) + (oct << 3));
    }
    __builtin_amdgcn_sched_barrier(0);   // pin S1-A issue before the barrier
    __syncthreads();

    // ---- MFMA S0 (weights fragment-major: 1KB contiguous per wave load) ----
    const unsigned short* bw = wtb + wave * 9216 + lane * 8;
    const unsigned short* arow = s_xoff + l16 * XSTR + quad * 8;
    float4a acc0 = {0.f, 0.f, 0.f, 0.f};
    #pragma unroll
    for (int ks = 0; ks < 18; ++ks) {
        const short8 a = *(const short8*)(arow + ks * 32);
        const short8 bf = *(const short8*)(bw + ks * 512);
        acc0 = __builtin_amdgcn_mfma_f32_16x16x32_bf16(a, bf, acc0, 0, 0, 0);
    }
    epilogue_seg(acc0, b, h, w0, wave, quad, l16, relu, nhwc_out, addsrc, out);

    __syncthreads();   // all MFMA-S0 LDS reads done; safe to overwrite s_xoff

    // ---- segment 1: issue round-B, comb2 A (hides B), comb2 B ----
    uint4 F[2][4];
    #pragma unroll
    for (int t = 0; t < 2; ++t) {
        F[t][0] = *(const uint4*)(srcb + (L1[3 + t].x << 6) + (oct << 3));
        F[t][1] = *(const uint4*)(srcb + (L1[3 + t].y << 6) + (oct << 3));
        F[t][2] = *(const uint4*)(srcb + (L1[3 + t].z << 6) + (oct << 3));
        F[t][3] = *(const uint4*)(srcb + (L1[3 + t].w << 6) + (oct << 3));
    }
    #pragma unroll
    for (int t = 0; t < 3; ++t) {
        const uint4 r = comb16(E[t][0], E[t][1], E[t][2], E[t][3], G1[t]);
        *(uint4*)(s_dst + (nT[t] << 6) + (oct << 3)) = r;
    }
    #pragma unroll
    for (int t = 0; t < 2; ++t) {
        const uint4 r = comb16(F[t][0], F[t][1], F[t][2], F[t][3], G1[3 + t]);
        *(uint4*)(s_dst + (nT[3 + t] << 6) + (oct << 3)) = r;
    }
    __syncthreads();

    // ---- MFMA S1 + epilogue ----
    float4a acc1 = {0.f, 0.f, 0.f, 0.f};
    #pragma unroll
    for (int ks = 0; ks < 18; ++ks) {
        const short8 a = *(const short8*)(arow + ks * 32);
        const short8 bf = *(const short8*)(bw + ks * 512);
        acc1 = __builtin_amdgcn_mfma_f32_16x16x32_bf16(a, bf, acc1, 0, 0, 0);
    }
    epilogue_seg(acc1, b, h, w0 + 16, wave, quad, l16, relu, nhwc_out, addsrc, out);
}

// ---------------------------------------------------------------------------
extern "C" void kernel_launch(void* const* d_in, const int* in_sizes, int n_in,
                              void* d_out, int out_size, void* d_ws, size_t ws_size,
                              hipStream_t stream) {
    const float* x      = (const float*)d_in[0];
    const float* w_off1 = (const float*)d_in[1];
    const float* b_off1 = (const float*)d_in[2];
    const float* w1     = (const float*)d_in[3];
    const float* w_off2 = (const float*)d_in[4];
    const float* b_off2 = (const float*)d_in[5];
    const float* w2     = (const float*)d_in[6];
    float* outp = (float*)d_out;

    // workspace: 16 MB xT + 16 MB midT + packed weights + record table
    char* ws = (char*)d_ws;
    unsigned short* xT   = (unsigned short*)ws;                     // 16777216 B
    unsigned short* midT = (unsigned short*)(ws + 16777216);        // 16777216 B
    unsigned short* w1b  = (unsigned short*)(ws + 33554432);                    // 73728
    unsigned short* w2b  = (unsigned short*)(ws + 33554432 + 73728);            // 73728
    unsigned short* wob1 = (unsigned short*)(ws + 33554432 + 2 * 73728);        // 36864
    unsigned short* wob2 = (unsigned short*)(ws + 33554432 + 2 * 73728 + 36864);// 36864
    const size_t fixed = 33554432 + 2 * 73728 + 2 * 36864;          // 33,775,616
    uint2* tbl = (uint2*)(ws + fixed);

    // record table: 36,864 B per image row (both batches). Chunk rows if tight.
    int R = 256;
    if (ws_size != 0) {
        size_t avail = (ws_size > fixed) ? (ws_size - fixed) : 0;
        while (R > 32 && (size_t)R * 36864ull > avail) R >>= 1;
    }

    k_pack_all<<<432, 256, 0, stream>>>(w1, w2, w_off1, w_off2, w1b, w2b, wob1, wob2);

    dim3 gT(1024, 2);
    k_transpose_bf<<<gT, 256, 0, stream>>>(x, xT);

    // layer 1: offsets/geometry -> records; gather-conv(x), ReLU -> midT (NHWC)
    for (int r0 = 0; r0 < 256; r0 += R) {
        dim3 gG(4, R, 2), gC(8, R, 2);
        k_geom<<<gG, 256, 0, stream>>>(xT, wob1, b_off1, tbl, r0, R);
        k_gconv<<<gC, 256, 0, stream>>>(xT, tbl, w1b, nullptr, midT, 1, 1, r0, R);
    }
    // layer 2: offsets/geometry from mid; gather-conv(mid) + x residual -> out
    for (int r0 = 0; r0 < 256; r0 += R) {
        dim3 gG(4, R, 2), gC(8, R, 2);
        k_geom<<<gG, 256, 0, stream>>>(midT, wob2, b_off2, tbl, r0, R);
        k_gconv<<<gC, 256, 0, stream>>>(midT, tbl, w2b, x, outp, 0, 0, r0, R);
    }
}